// Round 7
// baseline (195.123 us; speedup 1.0000x reference)
//
#include <hip/hip_runtime.h>

#define T   512
#define B   512
#define NT  64
#define QS  16            // steps per staging quarter
#define NQ  (T / QS)      // 32 quarters
#define RING 4            // LDS ring: 4 quarters, lead distance 3

typedef short bf16x8 __attribute__((ext_vector_type(8)));  // 8 bf16 (4 VGPRs)
typedef float f32x4  __attribute__((ext_vector_type(4)));

__device__ __forceinline__ float rflf(float x) {
    return __uint_as_float(__builtin_amdgcn_readfirstlane(__float_as_uint(x)));
}

__device__ __forceinline__ unsigned rne_bf16(float f) {   // RNE f32->bf16 bits
    unsigned u = __float_as_uint(f);
    u += 0x7fffu + ((u >> 16) & 1u);
    return u >> 16;
}
__device__ __forceinline__ int pk_bf16_rne(float lo, float hi) {
    return (int)(rne_bf16(lo) | (rne_bf16(hi) << 16));
}

// ---------------------------------------------------------------------------
// Fused CRF. Grid: [0,512) denominator chains (one single-wave block per
// batch), [512,1024) numerator gather waves.
//
// Denominator core (R6 was issue-bound at ~160 VALU instr/step; the 64-term
// broadcast matvec moves to the MFMA pipe):
//   A-frag: q replicated in all 16 rows (A[m][k]=q_k) -> every C row = q*E.
//   B-frags: E = exp(trans), 4 N-tiles x 2 K-halves, constant in 32 VGPRs.
//   8x v_mfma_f32_16x16x32_bf16 per step; lane j takes p_j from tile j>>4,
//   col j&15 (C layout col=lane&15 -> 3 cndmask select; any reg, rows equal).
//   A rebuild: dpp neighbor swap + v_perm bf16-pair pack (even lanes hold
//   (q_2i,q_2i+1)) + 8 ds_bpermute pulls.
//   bf16 has f32 exponent range -> renorm (power-of-2 via lane-0 exponent,
//   K += k) only every 4 steps; growth <= ~2^30 in between, f32-safe.
// X = exp(emission) staged through the R6-proven f32 LDS ring (loads lead by
// 3-4 quarters); mask via per-64-step ballot; no global access on the chain.
// ---------------------------------------------------------------------------
__global__ __launch_bounds__(64) void crf_fused(
    const float* __restrict__ emissions,  // [T, B, NT]
    const int*   __restrict__ tags,       // [T, B]
    const int*   __restrict__ mask,       // [T, B]
    const float* __restrict__ startT,     // [NT]
    const float* __restrict__ endT,       // [NT]
    const float* __restrict__ trans,      // [NT, NT]
    float* __restrict__ out)
{
    const int j = threadIdx.x;

    __shared__ __align__(16) float ebuf[RING][QS][NT];   // X = exp(e), 16 KB

    if (blockIdx.x < B) {
        // =============== denominator chain, b = blockIdx.x ==================
        const int b    = blockIdx.x;
        const int n    = j & 15;    // col within a tile
        const int quad = j >> 4;

        // B-frags: Bf[nt][h] elem e: E[k = h*32+quad*8+e][nt*16+n]
        bf16x8 Bf[4][2];
#pragma unroll
        for (int nt = 0; nt < 4; ++nt)
#pragma unroll
            for (int h = 0; h < 2; ++h) {
                int dw[4];
#pragma unroll
                for (int e2 = 0; e2 < 4; ++e2) {
                    const int k0 = h * 32 + quad * 8 + 2 * e2;
                    const float v0 = __expf(trans[k0 * NT + nt * 16 + n]);
                    const float v1 = __expf(trans[(k0 + 1) * NT + nt * 16 + n]);
                    dw[e2] = pk_bf16_rne(v0, v1);
                }
                int4 t4 = {dw[0], dw[1], dw[2], dw[3]};
                Bf[nt][h] = __builtin_bit_cast(bf16x8, t4);
            }

        // staging: lane j covers step 4k+(j>>4) of a quarter, cols (j&15)*4
        const int jr   = j >> 4;
        const int col0 = (j & 15) * 4;
        float4 sA[4];

        auto issue_q = [&](int g) {
#pragma unroll
            for (int k = 0; k < 4; ++k) {
                const int t = g * QS + 4 * k + jr;
                sA[k] = *(const float4*)&emissions[((size_t)t * B + b) * NT + col0];
            }
        };
        auto write_q = [&](int g) {   // exp() applied here, off the chain
#pragma unroll
            for (int k = 0; k < 4; ++k) {
                float4 w;
                w.x = __expf(sA[k].x); w.y = __expf(sA[k].y);
                w.z = __expf(sA[k].z); w.w = __expf(sA[k].w);
                *(float4*)&ebuf[g & (RING - 1)][4 * k + jr][col0] = w;
            }
        };

        for (int g = 0; g < 3; ++g) { issue_q(g); write_q(g); }
        issue_q(3);

        // t = 0 init
        const float e0  = emissions[(size_t)b * NT + j];
        const float sc0 = startT[j] + e0;
        const float S0  = rflf(sc0);
        float q = __expf(sc0 - S0);
        int   K = 0;

        const int base0 = quad * 8 * 4;   // byte addr of lane quad*8

        int mpre = mask[j * B + b];       // chunk-0 mask column
        unsigned long long mbc = 0;

        for (int x = 0; x < NQ; ++x) {
            const int gw = (x + 3 < NQ) ? x + 3 : NQ - 1;
            write_q(gw);
            const int gl = (x + 4 < NQ) ? x + 4 : NQ - 1;
            issue_q(gl);

            if ((x & 3) == 0) {           // 64-step chunk boundary
                mbc = __ballot(mpre != 0);
                const int cn = ((x >> 2) + 1 < 8) ? (x >> 2) + 1 : 7;
                mpre = mask[(cn * 64 + j) * B + b];
            }

            const int tt0 = (x == 0) ? 1 : 0;
#pragma unroll 4
            for (int tt = tt0; tt < QS; ++tt) {
                const float X = ebuf[x & (RING - 1)][tt][j];  // only DS read

                // ---- build A (q in all rows): pack pairs, bpermute pulls ---
                const int qi    = __float_as_int(q);
                const int qswap = __builtin_amdgcn_update_dpp(0, qi, 0xB1, 0xF, 0xF, true);
                const int pk    = __builtin_amdgcn_perm(
                                     (unsigned)qswap, (unsigned)qi, 0x07060302u);
                int f0[4], f1[4];
#pragma unroll
                for (int d = 0; d < 4; ++d) {
                    f0[d] = __builtin_amdgcn_ds_bpermute(base0 + 8 * d, pk);
                    f1[d] = __builtin_amdgcn_ds_bpermute(base0 + 8 * d + 128, pk);
                }
                int4 i40 = {f0[0], f0[1], f0[2], f0[3]};
                int4 i41 = {f1[0], f1[1], f1[2], f1[3]};
                const bf16x8 a0 = __builtin_bit_cast(bf16x8, i40);
                const bf16x8 a1 = __builtin_bit_cast(bf16x8, i41);

                // ---- 8 MFMA: C_nt = q.E columns 16nt..16nt+15 --------------
                const f32x4 z = {0.f, 0.f, 0.f, 0.f};
                f32x4 c0 = __builtin_amdgcn_mfma_f32_16x16x32_bf16(a0, Bf[0][0], z, 0, 0, 0);
                f32x4 c1 = __builtin_amdgcn_mfma_f32_16x16x32_bf16(a0, Bf[1][0], z, 0, 0, 0);
                f32x4 c2 = __builtin_amdgcn_mfma_f32_16x16x32_bf16(a0, Bf[2][0], z, 0, 0, 0);
                f32x4 c3 = __builtin_amdgcn_mfma_f32_16x16x32_bf16(a0, Bf[3][0], z, 0, 0, 0);
                c0 = __builtin_amdgcn_mfma_f32_16x16x32_bf16(a1, Bf[0][1], c0, 0, 0, 0);
                c1 = __builtin_amdgcn_mfma_f32_16x16x32_bf16(a1, Bf[1][1], c1, 0, 0, 0);
                c2 = __builtin_amdgcn_mfma_f32_16x16x32_bf16(a1, Bf[2][1], c2, 0, 0, 0);
                c3 = __builtin_amdgcn_mfma_f32_16x16x32_bf16(a1, Bf[3][1], c3, 0, 0, 0);

                // ---- p_j: tile quad, col n, any reg (rows identical) -------
                float p = c0[0];
                p = (quad == 1) ? c1[0] : p;
                p = (quad == 2) ? c2[0] : p;
                p = (quad == 3) ? c3[0] : p;

                const int  ttc = ((x & 3) << 4) + tt;
                const bool mc  = (mbc >> ttc) & 1ull;
                const float qn = p * X;
                q = mc ? qn : q;

                if ((tt & 3) == 3) {   // power-of-2 renorm, every 4 steps
                    const int bits = __builtin_amdgcn_readfirstlane(__float_as_int(q));
                    const int k    = ((bits >> 23) & 255) - 127;
                    q *= __int_as_float((127 - k) << 23);
                    K += k;
                }
            }
        }

        // den_b = S0 + K*ln2 + log( sum_j q_j * exp(endT_j) )
        float v = q * __expf(endT[j]);
#pragma unroll
        for (int off = 32; off > 0; off >>= 1)
            v += __shfl_xor(v, off);
        if (j == 0)
            atomicAdd(out, -(S0 + (float)K * 0.69314718f + __logf(v)));

    } else {
        // =============== numerator wave, b = blockIdx.x - B =================
        const int b = blockIdx.x - B;

        float acc = 0.f;
        int   cnt = 0;
#pragma unroll
        for (int m = 0; m < T / 64; ++m) {
            const int t  = j + 64 * m;
            const int mv = mask[t * B + b];
            const int tg = tags[t * B + b];
            cnt += (int)__popcll(__ballot(mv != 0));
            if (t == 0) {
                acc += startT[tg] + emissions[(size_t)b * NT + tg];
            } else if (mv) {
                const int tp = tags[(t - 1) * B + b];
                acc += trans[tp * NT + tg]
                     + emissions[(size_t)(t * B + b) * NT + tg];
            }
        }
#pragma unroll
        for (int off = 32; off > 0; off >>= 1)
            acc += __shfl_xor(acc, off);
        if (j == 0) {
            const int last = tags[(size_t)(cnt - 1) * B + b];
            atomicAdd(out, acc + endT[last]);
        }
    }
}

extern "C" void kernel_launch(void* const* d_in, const int* in_sizes, int n_in,
                              void* d_out, int out_size, void* d_ws, size_t ws_size,
                              hipStream_t stream) {
    const float* emissions = (const float*)d_in[0];
    const int*   tags      = (const int*)  d_in[1];
    const int*   mask      = (const int*)  d_in[2];
    const float* startT    = (const float*)d_in[3];
    const float* endT      = (const float*)d_in[4];
    const float* trans     = (const float*)d_in[5];
    float* out = (float*)d_out;

    hipMemsetAsync(out, 0, sizeof(float), stream);
    crf_fused<<<2 * B, 64, 0, stream>>>(
        emissions, tags, mask, startT, endT, trans, out);
}